// Round 2
// baseline (247.142 us; speedup 1.0000x reference)
//
#include <hip/hip_runtime.h>
#include <stdint.h>

// B=16, S=8192, DIM=128, H=4, KV=2, D=64; tokens = 131072; out [16,16384,128] fp32.
//
// Per token t: Y[896] = W' x_t + bias, where
//   ch in [0,256):   q, ch = h*64+d          (raw-reshape order)
//   ch in [256,384): k, ch-256 = kv*64+d
//   ch in [384,896): vproj, ch-384 = jg*64 + kp*16 + jm   (kp = kv*2+p, j = jg*16+jm)
//        W'[ch][c] = sum_d Wo[j][p*64+d] * Wv'[kv*64+d][c]
// coeff[t][ro*4+kp] = 0.125 * sum_d q[2ro+p,d]*k[kv,d]*qmean[d],  qmean = mean_h q[h,:]
// out[t,ro,j] = sum_kp coeff[t][ro*4+kp] * vproj[jg*16+jm, kp]

using short8 = __attribute__((ext_vector_type(8))) short;
using f32x4  = __attribute__((ext_vector_type(4))) float;

constexpr int XSTR = 136;   // bf16 elems per x-row in LDS (128 + 8 pad)
constexpr int CSTR = 12;    // fp32 stride of coeff rows (pad for bank spread, 48B = b128-aligned)

__device__ __forceinline__ unsigned short f2bf(float f) {
    unsigned int u = __float_as_uint(f);
    u += 0x7FFFu + ((u >> 16) & 1u);          // RNE
    return (unsigned short)(u >> 16);
}

// ---------------- prep: build W' (bf16 [896][128]) and bias (fp32 [896]) ----------------
__global__ void prep_weights(const float* __restrict__ Wq, const float* __restrict__ bq,
                             const float* __restrict__ Wk, const float* __restrict__ bk,
                             const float* __restrict__ Wv, const float* __restrict__ bv,
                             const float* __restrict__ Wo,
                             unsigned short* __restrict__ Wp, float* __restrict__ bias)
{
    const int ch = blockIdx.x;      // 0..895
    const int c  = threadIdx.x;     // 0..127
    float w, b;
    if (ch < 256) {                 // q: ch = h*64+d  ->  Wq[hh][dd], hh=ch&3, dd=ch>>2
        const int hh = ch & 3, dd = ch >> 2;
        w = Wq[(hh * 64 + dd) * 128 + c];
        b = bq[hh * 64 + dd];
    } else if (ch < 384) {          // k: i = kv*64+d -> Wk[i&1][i>>1]
        const int i = ch - 256;
        const int kvh = i & 1, dd = i >> 1;
        w = Wk[(kvh * 64 + dd) * 128 + c];
        b = bk[kvh * 64 + dd];
    } else {                        // vproj, kp-interleaved: i = jg*64 + kp*16 + jm
        const int i  = ch - 384;
        const int jg = i >> 6, kp = (i >> 4) & 3, jm = i & 15;
        const int j  = jg * 16 + jm, kv = kp >> 1, p = kp & 1;
        float acc = 0.f, bacc = 0.f;
        #pragma unroll 8
        for (int d = 0; d < 64; ++d) {
            const int idx = kv * 64 + d;
            const int kvh = idx & 1, dd = idx >> 1;
            const float wo = Wo[j * 128 + p * 64 + d];
            acc  += wo * Wv[(kvh * 64 + dd) * 128 + c];
            bacc += wo * bv[kvh * 64 + dd];
        }
        w = acc; b = bacc;
    }
    Wp[ch * 128 + c] = f2bf(w);
    if (c == 0) bias[ch] = b;
}

// ---------------- fused main kernel ----------------
// grid 2048, block 256 (4 waves). 64 tokens/block. LDS 28.7 KB -> 4 blocks/CU.
__global__ __launch_bounds__(256, 4)
void fused_attn_kernel(const float* __restrict__ x,
                       const unsigned short* __restrict__ Wp,
                       const float* __restrict__ bias,
                       float* __restrict__ out)
{
    __shared__ __align__(16) unsigned short xlds[64 * XSTR];   // 17408 B
    __shared__ __align__(16) float partial[4 * 64 * 8];        //  8192 B
    __shared__ __align__(16) float coeff[64 * CSTR];           //  3072 B

    const int tid = threadIdx.x;
    const int l   = tid & 63;
    const int wv  = tid >> 6;       // wave 0..3
    const int lr  = l & 15, lg = l >> 4;
    const int g0  = blockIdx.x * 64;

    // ---- stage x tile (64x128 fp32 -> bf16 LDS, padded rows, coalesced loads) ----
    {
        const float4* xp = (const float4*)(x + (size_t)g0 * 128);
        #pragma unroll
        for (int i = 0; i < 8; ++i) {
            const int idx = i * 256 + tid;          // float4 index within tile
            float4 v = xp[idx];
            const int e = idx * 4;
            const int row = e >> 7, col = e & 127;
            ushort4 s;
            s.x = f2bf(v.x); s.y = f2bf(v.y); s.z = f2bf(v.z); s.w = f2bf(v.w);
            *(ushort4*)&xlds[row * XSTR + col] = s;
        }
    }
    __syncthreads();

    // ---- phase 1: q/k tiles for d-chunk dc = wv; lane-local attn products ----
    {
        const int dc = wv;
        int chb[6];
        #pragma unroll
        for (int n = 0; n < 4; ++n) chb[n] = n * 64 + dc * 16;          // q heads
        chb[4] = 256 + dc * 16;                                          // kv=0
        chb[5] = 320 + dc * 16;                                          // kv=1
        float tb[6];
        #pragma unroll
        for (int n = 0; n < 6; ++n) tb[n] = bias[chb[n] + lr];

        #pragma unroll
        for (int mh = 0; mh < 2; ++mh) {            // token halves of 32
            f32x4 acc[2][6];
            #pragma unroll
            for (int mi = 0; mi < 2; ++mi)
                #pragma unroll
                for (int n = 0; n < 6; ++n)
                    acc[mi][n] = (f32x4){0.f, 0.f, 0.f, 0.f};

            #pragma unroll
            for (int ks = 0; ks < 4; ++ks) {
                const int k0 = ks * 32 + lg * 8;
                short8 a0 = *(const short8*)&xlds[(mh * 32 +      lr) * XSTR + k0];
                short8 a1 = *(const short8*)&xlds[(mh * 32 + 16 + lr) * XSTR + k0];
                #pragma unroll
                for (int n = 0; n < 6; ++n) {
                    short8 bfr = *(const short8*)(Wp + (size_t)(chb[n] + lr) * 128 + k0);
                    acc[0][n] = __builtin_amdgcn_mfma_f32_16x16x32_bf16(a0, bfr, acc[0][n], 0, 0, 0);
                    acc[1][n] = __builtin_amdgcn_mfma_f32_16x16x32_bf16(a1, bfr, acc[1][n], 0, 0, 0);
                }
            }

            #pragma unroll
            for (int mi = 0; mi < 2; ++mi) {
                const int mf = mh * 2 + mi;
                float pa[4][8];
                #pragma unroll
                for (int r = 0; r < 4; ++r) {
                    const float q0 = acc[mi][0][r] + tb[0];
                    const float q1 = acc[mi][1][r] + tb[1];
                    const float q2 = acc[mi][2][r] + tb[2];
                    const float q3 = acc[mi][3][r] + tb[3];
                    const float k0v = acc[mi][4][r] + tb[4];
                    const float k1v = acc[mi][5][r] + tb[5];
                    const float qm  = 0.25f * (q0 + q1 + q2 + q3);
                    const float kt0 = k0v * qm, kt1 = k1v * qm;
                    // slot c = ro*4 + kv*2 + p; h = 2ro+p
                    pa[r][0] = q0 * kt0;  pa[r][1] = q1 * kt0;
                    pa[r][2] = q0 * kt1;  pa[r][3] = q1 * kt1;
                    pa[r][4] = q2 * kt0;  pa[r][5] = q3 * kt0;
                    pa[r][6] = q2 * kt1;  pa[r][7] = q3 * kt1;
                }
                // reduce over the 16 lanes (d within chunk)
                #pragma unroll
                for (int off = 1; off < 16; off <<= 1)
                    #pragma unroll
                    for (int r = 0; r < 4; ++r)
                        #pragma unroll
                        for (int c = 0; c < 8; ++c)
                            pa[r][c] += __shfl_xor(pa[r][c], off);
                // write partial[dc][tok][8]: lane (lr>>2)==r writes pair (lr&3)
                const int psel = lr & 3, rsel = lr >> 2;
                #pragma unroll
                for (int r = 0; r < 4; ++r) {
                    if (rsel == r) {
                        float e0 = pa[r][0], e1 = pa[r][1];
                        if (psel == 1) { e0 = pa[r][2]; e1 = pa[r][3]; }
                        if (psel == 2) { e0 = pa[r][4]; e1 = pa[r][5]; }
                        if (psel == 3) { e0 = pa[r][6]; e1 = pa[r][7]; }
                        const int tok = mf * 16 + lg * 4 + r;
                        *(float2*)&partial[(dc * 64 + tok) * 8 + 2 * psel] = make_float2(e0, e1);
                    }
                }
            }
        }
    }
    __syncthreads();

    // ---- finalize coeffs: sum 4 dc partials, fold 1/sqrt(64)=0.125 ----
    {
        const int tok = wv * 16 + (l >> 2);
        const int c2  = (l & 3) * 2;
        float s0 = 0.f, s1 = 0.f;
        #pragma unroll
        for (int dcc = 0; dcc < 4; ++dcc) {
            float2 v = *(const float2*)&partial[(dcc * 64 + tok) * 8 + c2];
            s0 += v.x; s1 += v.y;
        }
        *(float2*)&coeff[tok * CSTR + c2] = make_float2(s0 * 0.125f, s1 * 0.125f);
    }
    __syncthreads();

    // ---- phase 2: vproj MFMA + in-register combine + store ----
    {
        const int bb    = g0 >> 13;
        const int srow0 = bb * 16384 + 2 * (g0 & 8191);
        #pragma unroll
        for (int j2 = 0; j2 < 2; ++j2) {
            const int jg  = wv * 2 + j2;
            const int chb = 384 + jg * 64;          // + kp*16
            f32x4 acc[4][4];                         // [mf][kp]
            #pragma unroll
            for (int mf = 0; mf < 4; ++mf)
                #pragma unroll
                for (int kp = 0; kp < 4; ++kp)
                    acc[mf][kp] = (f32x4){0.f, 0.f, 0.f, 0.f};

            #pragma unroll
            for (int ks = 0; ks < 4; ++ks) {
                const int k0 = ks * 32 + lg * 8;
                short8 af[4];
                #pragma unroll
                for (int mf = 0; mf < 4; ++mf)
                    af[mf] = *(const short8*)&xlds[(mf * 16 + lr) * XSTR + k0];
                #pragma unroll
                for (int kp = 0; kp < 4; ++kp) {
                    short8 bfr = *(const short8*)(Wp + (size_t)(chb + kp * 16 + lr) * 128 + k0);
                    #pragma unroll
                    for (int mf = 0; mf < 4; ++mf)
                        acc[mf][kp] = __builtin_amdgcn_mfma_f32_16x16x32_bf16(af[mf], bfr, acc[mf][kp], 0, 0, 0);
                }
            }

            float bv0 = bias[chb + 0  + lr];
            float bv1 = bias[chb + 16 + lr];
            float bv2 = bias[chb + 32 + lr];
            float bv3 = bias[chb + 48 + lr];

            #pragma unroll
            for (int mf = 0; mf < 4; ++mf) {
                #pragma unroll
                for (int r = 0; r < 4; ++r) {
                    const int tok = mf * 16 + lg * 4 + r;
                    float4 cl = *(const float4*)&coeff[tok * CSTR];
                    float4 chi = *(const float4*)&coeff[tok * CSTR + 4];
                    const float a0 = acc[mf][0][r] + bv0;
                    const float a1 = acc[mf][1][r] + bv1;
                    const float a2 = acc[mf][2][r] + bv2;
                    const float a3 = acc[mf][3][r] + bv3;
                    const float o0 = cl.x * a0 + cl.y * a1 + cl.z * a2 + cl.w * a3;
                    const float o1 = chi.x * a0 + chi.y * a1 + chi.z * a2 + chi.w * a3;
                    float* dst = out + (size_t)(srow0 + 2 * tok) * 128 + jg * 16 + lr;
                    dst[0]   = o0;
                    dst[128] = o1;
                }
            }
        }
    }
}

extern "C" void kernel_launch(void* const* d_in, const int* in_sizes, int n_in,
                              void* d_out, int out_size, void* d_ws, size_t ws_size,
                              hipStream_t stream)
{
    (void)in_sizes; (void)n_in; (void)out_size; (void)ws_size;
    const float* x  = (const float*)d_in[0];
    const float* Wq = (const float*)d_in[1];
    const float* bq = (const float*)d_in[2];
    const float* Wk = (const float*)d_in[3];
    const float* bk = (const float*)d_in[4];
    const float* Wv = (const float*)d_in[5];
    const float* bv = (const float*)d_in[6];
    const float* Wo = (const float*)d_in[7];

    unsigned short* Wp   = (unsigned short*)d_ws;                    // 896*128 bf16
    float*          bias = (float*)((char*)d_ws + 896 * 128 * 2);    // 896 fp32

    prep_weights<<<896, 128, 0, stream>>>(Wq, bq, Wk, bk, Wv, bv, Wo, Wp, bias);
    fused_attn_kernel<<<2048, 256, 0, stream>>>(x, Wp, bias, (float*)d_out);
}

// Round 3
// 231.504 us; speedup vs baseline: 1.0676x; 1.0676x over previous
//
#include <hip/hip_runtime.h>
#include <stdint.h>

// B=16, S=8192, DIM=128, H=4, KV=2, D=64; tokens = 131072; out [16,16384,128] fp32.
//
// Per token t: Y[896] = W' x_t + bias, where
//   ch in [0,256):   q, ch = h*64+d          (raw-reshape order)
//   ch in [256,384): k, ch-256 = kv*64+d
//   ch in [384,896): vproj, ch-384 = jg*64 + kp*16 + jm   (kp = kv*2+p, j = jg*16+jm)
//        W'[ch][c] = sum_d Wo[j][p*64+d] * Wv'[kv*64+d][c]
// coeff[t][ro*4+kp] = 0.125 * sum_d q[2ro+p,d]*k[kv,d]*qmean[d],  qmean = mean_h q[h,:]
// out[t,ro,j] = sum_kp coeff[t][ro*4+kp] * vproj[jg*16+jm, kp]

using short8 = __attribute__((ext_vector_type(8))) short;
using f32x4  = __attribute__((ext_vector_type(4))) float;

constexpr int XSTR = 136;   // bf16 elems per x-row in LDS (128 + 8 pad)
constexpr int CSTR = 12;    // fp32 stride of coeff rows (48B, b128-aligned)

__device__ __forceinline__ unsigned short f2bf(float f) {
    unsigned int u = __float_as_uint(f);
    u += 0x7FFFu + ((u >> 16) & 1u);          // RNE
    return (unsigned short)(u >> 16);
}

// ---------------- prep: build W' (bf16 [896][128]) and bias (fp32 [896]) ----------------
__global__ void prep_weights(const float* __restrict__ Wq, const float* __restrict__ bq,
                             const float* __restrict__ Wk, const float* __restrict__ bk,
                             const float* __restrict__ Wv, const float* __restrict__ bv,
                             const float* __restrict__ Wo,
                             unsigned short* __restrict__ Wp, float* __restrict__ bias)
{
    const int ch = blockIdx.x;      // 0..895
    const int c  = threadIdx.x;     // 0..127
    float w, b;
    if (ch < 256) {                 // q: ch = h*64+d  ->  Wq[ch&3][ch>>2]
        const int hh = ch & 3, dd = ch >> 2;
        w = Wq[(hh * 64 + dd) * 128 + c];
        b = bq[hh * 64 + dd];
    } else if (ch < 384) {          // k: i = kv*64+d -> Wk[i&1][i>>1]
        const int i = ch - 256;
        const int kvh = i & 1, dd = i >> 1;
        w = Wk[(kvh * 64 + dd) * 128 + c];
        b = bk[kvh * 64 + dd];
    } else {                        // vproj, kp-interleaved: i = jg*64 + kp*16 + jm
        const int i  = ch - 384;
        const int jg = i >> 6, kp = (i >> 4) & 3, jm = i & 15;
        const int j  = jg * 16 + jm, kv = kp >> 1, p = kp & 1;
        float acc = 0.f, bacc = 0.f;
        #pragma unroll 8
        for (int d = 0; d < 64; ++d) {
            const int idx = kv * 64 + d;
            const int kvh = idx & 1, dd = idx >> 1;
            const float wo = Wo[j * 128 + p * 64 + d];
            acc  += wo * Wv[(kvh * 64 + dd) * 128 + c];
            bacc += wo * bv[kvh * 64 + dd];
        }
        w = acc; b = bacc;
    }
    Wp[ch * 128 + c] = f2bf(w);
    if (c == 0) bias[ch] = b;
}

// ---------------- fused main kernel ----------------
// grid 2048, block 256 (4 waves). 64 tokens/block. LDS 36 KB -> 4 blocks/CU.
__global__ __launch_bounds__(256, 4)
void fused_attn_kernel(const float* __restrict__ x,
                       const unsigned short* __restrict__ Wp,
                       const float* __restrict__ bias,
                       float* __restrict__ out)
{
    __shared__ __align__(16) unsigned short xlds[64 * XSTR];   // 17408 B
    __shared__ __align__(16) float scratch[4096];              // 16384 B: phase1 partial / phase2 obuf
    __shared__ __align__(16) float coeff[64 * CSTR];           //  3072 B

    float* partial = scratch;    // [4 dc][64 tok][8]  (2048 floats used)
    float* obuf    = scratch;    // [16 tok][2 ro][128] swizzled (4096 floats)

    const int tid = threadIdx.x;
    const int l   = tid & 63;
    const int wv  = tid >> 6;       // wave 0..3
    const int lr  = l & 15, lg = l >> 4;
    const int g0  = blockIdx.x * 64;

    // ---- stage x tile (64x128 fp32 -> bf16 LDS, padded rows, coalesced loads) ----
    {
        const float4* xp = (const float4*)(x + (size_t)g0 * 128);
        #pragma unroll
        for (int i = 0; i < 8; ++i) {
            const int idx = i * 256 + tid;          // float4 index within tile
            float4 v = xp[idx];
            const int e = idx * 4;
            const int row = e >> 7, col = e & 127;
            ushort4 s;
            s.x = f2bf(v.x); s.y = f2bf(v.y); s.z = f2bf(v.z); s.w = f2bf(v.w);
            *(ushort4*)&xlds[row * XSTR + col] = s;
        }
    }
    __syncthreads();

    // ---- phase 1: q/k tiles for d-chunk dc = wv; lane-local attn products ----
    {
        const int dc = wv;
        int chb[6];
        #pragma unroll
        for (int n = 0; n < 4; ++n) chb[n] = n * 64 + dc * 16;          // q heads
        chb[4] = 256 + dc * 16;                                          // kv=0
        chb[5] = 320 + dc * 16;                                          // kv=1
        float tb[6];
        #pragma unroll
        for (int n = 0; n < 6; ++n) tb[n] = bias[chb[n] + lr];

        #pragma unroll
        for (int mh = 0; mh < 2; ++mh) {            // token halves of 32
            f32x4 acc[2][6];
            #pragma unroll
            for (int mi = 0; mi < 2; ++mi)
                #pragma unroll
                for (int n = 0; n < 6; ++n)
                    acc[mi][n] = (f32x4){0.f, 0.f, 0.f, 0.f};

            #pragma unroll
            for (int ks = 0; ks < 4; ++ks) {
                const int k0 = ks * 32 + lg * 8;
                short8 a0 = *(const short8*)&xlds[(mh * 32 +      lr) * XSTR + k0];
                short8 a1 = *(const short8*)&xlds[(mh * 32 + 16 + lr) * XSTR + k0];
                #pragma unroll
                for (int n = 0; n < 6; ++n) {
                    short8 bfr = *(const short8*)(Wp + (size_t)(chb[n] + lr) * 128 + k0);
                    acc[0][n] = __builtin_amdgcn_mfma_f32_16x16x32_bf16(a0, bfr, acc[0][n], 0, 0, 0);
                    acc[1][n] = __builtin_amdgcn_mfma_f32_16x16x32_bf16(a1, bfr, acc[1][n], 0, 0, 0);
                }
            }

            #pragma unroll
            for (int mi = 0; mi < 2; ++mi) {
                const int mf = mh * 2 + mi;
                float pa[4][8];
                #pragma unroll
                for (int r = 0; r < 4; ++r) {
                    const float q0 = acc[mi][0][r] + tb[0];
                    const float q1 = acc[mi][1][r] + tb[1];
                    const float q2 = acc[mi][2][r] + tb[2];
                    const float q3 = acc[mi][3][r] + tb[3];
                    const float k0v = acc[mi][4][r] + tb[4];
                    const float k1v = acc[mi][5][r] + tb[5];
                    const float qm  = 0.25f * (q0 + q1 + q2 + q3);
                    const float kt0 = k0v * qm, kt1 = k1v * qm;
                    // slot c = ro*4 + kv*2 + p; h = 2ro+p
                    pa[r][0] = q0 * kt0;  pa[r][1] = q1 * kt0;
                    pa[r][2] = q0 * kt1;  pa[r][3] = q1 * kt1;
                    pa[r][4] = q2 * kt0;  pa[r][5] = q3 * kt0;
                    pa[r][6] = q2 * kt1;  pa[r][7] = q3 * kt1;
                }
                // reduce over the 16 lanes (d within chunk)
                #pragma unroll
                for (int off = 1; off < 16; off <<= 1)
                    #pragma unroll
                    for (int r = 0; r < 4; ++r)
                        #pragma unroll
                        for (int c = 0; c < 8; ++c)
                            pa[r][c] += __shfl_xor(pa[r][c], off);
                // write partial[dc][tok][8]: lane (lr>>2)==r writes pair (lr&3)
                const int psel = lr & 3, rsel = lr >> 2;
                #pragma unroll
                for (int r = 0; r < 4; ++r) {
                    if (rsel == r) {
                        float e0 = pa[r][0], e1 = pa[r][1];
                        if (psel == 1) { e0 = pa[r][2]; e1 = pa[r][3]; }
                        if (psel == 2) { e0 = pa[r][4]; e1 = pa[r][5]; }
                        if (psel == 3) { e0 = pa[r][6]; e1 = pa[r][7]; }
                        const int tok = mf * 16 + lg * 4 + r;
                        *(float2*)&partial[(dc * 64 + tok) * 8 + 2 * psel] = make_float2(e0, e1);
                    }
                }
            }
        }
    }
    __syncthreads();

    // ---- finalize coeffs: sum 4 dc partials, fold 1/sqrt(64)=0.125 ----
    {
        const int tok = wv * 16 + (l >> 2);
        const int c2  = (l & 3) * 2;
        float s0 = 0.f, s1 = 0.f;
        #pragma unroll
        for (int dcc = 0; dcc < 4; ++dcc) {
            float2 v = *(const float2*)&partial[(dcc * 64 + tok) * 8 + c2];
            s0 += v.x; s1 += v.y;
        }
        *(float2*)&coeff[tok * CSTR + c2] = make_float2(s0 * 0.125f, s1 * 0.125f);
    }
    __syncthreads();    // also: all partial reads done before obuf overwrites scratch

    // ---- phase 2: per 16-token group: vproj MFMA + combine -> obuf -> coalesced store ----
    {
        const int bb    = g0 >> 13;
        const int srow0 = bb * 16384 + 2 * (g0 & 8191);

        // biases for this wave's 2 j-groups x 4 kp (hoisted)
        float bvv[2][4];
        #pragma unroll
        for (int j2 = 0; j2 < 2; ++j2)
            #pragma unroll
            for (int kp = 0; kp < 4; ++kp)
                bvv[j2][kp] = bias[384 + (wv * 2 + j2) * 64 + kp * 16 + lr];

        #pragma unroll
        for (int mf = 0; mf < 4; ++mf) {
            f32x4 acc[2][4];                         // [j2][kp]
            #pragma unroll
            for (int j2 = 0; j2 < 2; ++j2)
                #pragma unroll
                for (int kp = 0; kp < 4; ++kp)
                    acc[j2][kp] = (f32x4){0.f, 0.f, 0.f, 0.f};

            #pragma unroll
            for (int ks = 0; ks < 4; ++ks) {
                const int k0 = ks * 32 + lg * 8;
                short8 af = *(const short8*)&xlds[(mf * 16 + lr) * XSTR + k0];
                #pragma unroll
                for (int j2 = 0; j2 < 2; ++j2) {
                    const int chb = 384 + (wv * 2 + j2) * 64;
                    #pragma unroll
                    for (int kp = 0; kp < 4; ++kp) {
                        short8 bfr = *(const short8*)(Wp + (size_t)(chb + kp * 16 + lr) * 128 + k0);
                        acc[j2][kp] = __builtin_amdgcn_mfma_f32_16x16x32_bf16(af, bfr, acc[j2][kp], 0, 0, 0);
                    }
                }
            }

            // combine with coeffs, write swizzled obuf
            #pragma unroll
            for (int j2 = 0; j2 < 2; ++j2) {
                const int jg = wv * 2 + j2;
                #pragma unroll
                for (int r = 0; r < 4; ++r) {
                    const int tokL = lg * 4 + r;                 // 0..15 within group
                    const int tok  = mf * 16 + tokL;
                    float4 cl  = *(const float4*)&coeff[tok * CSTR];
                    float4 chi = *(const float4*)&coeff[tok * CSTR + 4];
                    const float a0 = acc[j2][0][r] + bvv[j2][0];
                    const float a1 = acc[j2][1][r] + bvv[j2][1];
                    const float a2 = acc[j2][2][r] + bvv[j2][2];
                    const float a3 = acc[j2][3][r] + bvv[j2][3];
                    const float o0 = cl.x  * a0 + cl.y  * a1 + cl.z  * a2 + cl.w  * a3;
                    const float o1 = chi.x * a0 + chi.y * a1 + chi.z * a2 + chi.w * a3;
                    const int log0 = tokL * 256 + jg * 16 + lr;  // ro=0
                    const int sw   = (lg & 3) << 4;              // (log>>10)&3 == lg
                    obuf[(log0      ) ^ sw] = o0;
                    obuf[(log0 + 128) ^ sw] = o1;
                }
            }
            __syncthreads();

            // coalesced copy: 16 tokens x 2 rows x 512B = 16 KB contiguous
            float* dst = out + (size_t)(srow0 + 32 * mf) * 128;
            #pragma unroll
            for (int it = 0; it < 4; ++it) {
                const int log = it * 1024 + tid * 4;
                const int sw  = (it & 3) << 4;                   // (log>>10)&3 == it
                float4 v = *(const float4*)&obuf[log ^ sw];
                *(float4*)(dst + log) = v;
            }
            __syncthreads();
        }
    }
}

extern "C" void kernel_launch(void* const* d_in, const int* in_sizes, int n_in,
                              void* d_out, int out_size, void* d_ws, size_t ws_size,
                              hipStream_t stream)
{
    (void)in_sizes; (void)n_in; (void)out_size; (void)ws_size;
    const float* x  = (const float*)d_in[0];
    const float* Wq = (const float*)d_in[1];
    const float* bq = (const float*)d_in[2];
    const float* Wk = (const float*)d_in[3];
    const float* bk = (const float*)d_in[4];
    const float* Wv = (const float*)d_in[5];
    const float* bv = (const float*)d_in[6];
    const float* Wo = (const float*)d_in[7];

    unsigned short* Wp   = (unsigned short*)d_ws;                    // 896*128 bf16
    float*          bias = (float*)((char*)d_ws + 896 * 128 * 2);    // 896 fp32

    prep_weights<<<896, 128, 0, stream>>>(Wq, bq, Wk, bk, Wv, bv, Wo, Wp, bias);
    fused_attn_kernel<<<2048, 256, 0, stream>>>(x, Wp, bias, (float*)d_out);
}

// Round 4
// 61.421 us; speedup vs baseline: 4.0238x; 3.7692x over previous
//
#include <hip/hip_runtime.h>
#include <stdint.h>

// B=16, S=8192, DIM=128, H=4, KV=2, D=64; tokens = 131072; out [16,16384,128] fp32.
//
// Per token t: Y[896] = W' x_t + bias:
//   ch [0,256):   q, ch = h*64+d
//   ch [256,384): k, ch-256 = kv*64+d
//   ch [384,896): vproj, ch-384 = jg*64 + kp*16 + jm  (kp=kv*2+p, j=jg*16+jm)
// coeff[t][ro*4+kp] = 0.125 * sum_d q[2ro+p,d]*k[kv,d]*qmean[d]
// out[t-row(2t+ro), j] = sum_kp coeff * vproj
//
// Structure: 256 blocks x 512 thr (8 waves), 1 block/CU. Waves 0-3 = qk
// (phase1, swapped-operand MFMA, B-in-regs 96 VGPR), waves 4-7 = vproj
// (phase2, B-in-regs 128 VGPR). 8 tiles of 64 tokens per block, software
// pipeline, one barrier per iteration. x triple-buffered in LDS.

using short8 = __attribute__((ext_vector_type(8))) short;
using f32x4  = __attribute__((ext_vector_type(4))) float;

constexpr int XSTR = 136;     // bf16 elems per x-row in LDS (128+8)
constexpr int PSTR = 12;      // floats per partial row (8 used, 16B-aligned stride)
constexpr int T_TILES = 8;

__device__ __forceinline__ unsigned short f2bf(float f) {
    unsigned int u = __float_as_uint(f);
    u += 0x7FFFu + ((u >> 16) & 1u);          // RNE
    return (unsigned short)(u >> 16);
}

// ---------------- prep: build W' (bf16 [896][128]) and bias (fp32 [896]) ----------------
__global__ void prep_weights(const float* __restrict__ Wq, const float* __restrict__ bq,
                             const float* __restrict__ Wk, const float* __restrict__ bk,
                             const float* __restrict__ Wv, const float* __restrict__ bv,
                             const float* __restrict__ Wo,
                             unsigned short* __restrict__ Wp, float* __restrict__ bias)
{
    const int ch = blockIdx.x;      // 0..895
    const int c  = threadIdx.x;     // 0..127
    float w, b;
    if (ch < 256) {                 // q
        const int hh = ch & 3, dd = ch >> 2;
        w = Wq[(hh * 64 + dd) * 128 + c];
        b = bq[hh * 64 + dd];
    } else if (ch < 384) {          // k
        const int i = ch - 256;
        const int kvh = i & 1, dd = i >> 1;
        w = Wk[(kvh * 64 + dd) * 128 + c];
        b = bk[kvh * 64 + dd];
    } else {                        // vproj, kp-interleaved
        const int i  = ch - 384;
        const int jg = i >> 6, kp = (i >> 4) & 3, jm = i & 15;
        const int j  = jg * 16 + jm, kv = kp >> 1, p = kp & 1;
        float acc = 0.f, bacc = 0.f;
        #pragma unroll 8
        for (int d = 0; d < 64; ++d) {
            const int idx = kv * 64 + d;
            const int kvh = idx & 1, dd = idx >> 1;
            const float wo = Wo[j * 128 + p * 64 + d];
            acc  += wo * Wv[(kvh * 64 + dd) * 128 + c];
            bacc += wo * bv[kvh * 64 + dd];
        }
        w = acc; b = bacc;
    }
    Wp[ch * 128 + c] = f2bf(w);
    if (c == 0) bias[ch] = b;
}

// ---- x staging helpers: 8 rows per wave, issue-early / write-late (T14) ----
__device__ __forceinline__ void stage8_load(const float* __restrict__ x, int tb, int row0,
                                            int l, float4* xv)
{
    const int row = row0 + (l >> 3);
    const float* src = x + (size_t)(tb + row) * 128 + (l & 7) * 4;
    #pragma unroll
    for (int j = 0; j < 4; ++j) xv[j] = *(const float4*)(src + 32 * j);
}
__device__ __forceinline__ void stage8_write(unsigned short* __restrict__ xb, int row0,
                                             int l, const float4* xv)
{
    const int row = row0 + (l >> 3);
    #pragma unroll
    for (int j = 0; j < 4; ++j) {
        ushort4 s;
        s.x = f2bf(xv[j].x); s.y = f2bf(xv[j].y); s.z = f2bf(xv[j].z); s.w = f2bf(xv[j].w);
        *(ushort4*)&xb[row * XSTR + (l & 7) * 4 + 32 * j] = s;
    }
}

// ---------------- fused main kernel ----------------
__global__ __launch_bounds__(512, 2)
void fused_attn_kernel(const float* __restrict__ x,
                       const unsigned short* __restrict__ Wp,
                       const float* __restrict__ bias,
                       float* __restrict__ out)
{
    __shared__ __align__(16) unsigned short xlds[3][64 * XSTR];       // 52224 B
    __shared__ __align__(16) float partial[2][4][64][PSTR];           // 24576 B
    __shared__ __align__(16) float coeffw[4][64][8];                  //  8192 B
    __shared__ __align__(16) float obufs[4][1024];                    // 16384 B

    const int tid = threadIdx.x;
    const int l   = tid & 63;
    const int wv  = tid >> 6;           // 0..7
    const int lr  = l & 15, lg = l >> 4;
    const int tok0 = blockIdx.x * (T_TILES * 64);

    if (wv < 4) {
        // ================= qk waves: phase1 producer =================
        const int dc = wv;
        int chb[6];
        #pragma unroll
        for (int n = 0; n < 4; ++n) chb[n] = n * 64 + dc * 16;
        chb[4] = 256 + dc * 16;
        chb[5] = 320 + dc * 16;

        // persistent A-regs (Wp fragments) + bias
        short8 areg[24];
        #pragma unroll
        for (int n = 0; n < 6; ++n)
            #pragma unroll
            for (int ks = 0; ks < 4; ++ks)
                areg[n * 4 + ks] = *(const short8*)(Wp + (size_t)(chb[n] + lr) * 128 + ks * 32 + lg * 8);
        f32x4 biasv[6];
        #pragma unroll
        for (int n = 0; n < 6; ++n)
            biasv[n] = *(const f32x4*)(bias + chb[n] + lg * 4);

        auto phase1 = [&](const unsigned short* __restrict__ xb, int pb) {
            #pragma unroll
            for (int th = 0; th < 2; ++th) {
                f32x4 acc[2][6];
                #pragma unroll
                for (int ti = 0; ti < 2; ++ti)
                    #pragma unroll
                    for (int n = 0; n < 6; ++n)
                        acc[ti][n] = (f32x4){0.f, 0.f, 0.f, 0.f};
                #pragma unroll
                for (int ks = 0; ks < 4; ++ks) {
                    #pragma unroll
                    for (int ti = 0; ti < 2; ++ti) {
                        const int tf = th * 2 + ti;
                        short8 bfr = *(const short8*)&xb[(tf * 16 + lr) * XSTR + ks * 32 + lg * 8];
                        #pragma unroll
                        for (int n = 0; n < 6; ++n)
                            acc[ti][n] = __builtin_amdgcn_mfma_f32_16x16x32_bf16(
                                areg[n * 4 + ks], bfr, acc[ti][n], 0, 0, 0);
                    }
                }
                // epilogue: lane = token, channels register-local
                #pragma unroll
                for (int ti = 0; ti < 2; ++ti) {
                    const int tf = th * 2 + ti;
                    float pa[8];
                    #pragma unroll
                    for (int c = 0; c < 8; ++c) pa[c] = 0.f;
                    #pragma unroll
                    for (int r = 0; r < 4; ++r) {
                        const float q0 = acc[ti][0][r] + biasv[0][r];
                        const float q1 = acc[ti][1][r] + biasv[1][r];
                        const float q2 = acc[ti][2][r] + biasv[2][r];
                        const float q3 = acc[ti][3][r] + biasv[3][r];
                        const float k0v = acc[ti][4][r] + biasv[4][r];
                        const float k1v = acc[ti][5][r] + biasv[5][r];
                        const float qm  = 0.25f * (q0 + q1 + q2 + q3);
                        const float kt0 = k0v * qm, kt1 = k1v * qm;
                        pa[0] += q0 * kt0; pa[1] += q1 * kt0;
                        pa[2] += q0 * kt1; pa[3] += q1 * kt1;
                        pa[4] += q2 * kt0; pa[5] += q3 * kt0;
                        pa[6] += q2 * kt1; pa[7] += q3 * kt1;
                    }
                    #pragma unroll
                    for (int c = 0; c < 8; ++c) pa[c] += __shfl_xor(pa[c], 16);
                    #pragma unroll
                    for (int c = 0; c < 8; ++c) pa[c] += __shfl_xor(pa[c], 32);
                    if (lg == 0) {
                        f32x4 p0 = {pa[0], pa[1], pa[2], pa[3]};
                        f32x4 p1 = {pa[4], pa[5], pa[6], pa[7]};
                        float* dst = &partial[pb][dc][tf * 16 + lr][0];
                        *(f32x4*)(dst)     = p0;
                        *(f32x4*)(dst + 4) = p1;
                    }
                }
            }
        };

        // prologue
        {
            float4 xv[4];
            stage8_load(x, tok0, wv * 8, l, xv);
            stage8_write(xlds[0], wv * 8, l, xv);
        }
        __syncthreads();                       // B1: x0 ready
        phase1(xlds[0], 0);
        __syncthreads();                       // B2: partial[0] + x1 ready

        for (int t = 0; t < T_TILES; ++t) {
            float4 xv[4];
            const bool do_stage = (t < T_TILES - 2);
            if (do_stage) stage8_load(x, tok0 + (t + 2) * 64, wv * 8, l, xv);
            if (t < T_TILES - 1) phase1(xlds[(t + 1) % 3], (t + 1) & 1);
            if (do_stage) stage8_write(xlds[(t + 2) % 3], wv * 8, l, xv);
            __syncthreads();
        }
    } else {
        // ================= v waves: phase2 consumer =================
        const int jgp = wv - 4;

        short8 breg[32];                       // [(j2*4+kp)*4 + ks]
        #pragma unroll
        for (int j2 = 0; j2 < 2; ++j2)
            #pragma unroll
            for (int kp = 0; kp < 4; ++kp)
                #pragma unroll
                for (int ks = 0; ks < 4; ++ks)
                    breg[(j2 * 4 + kp) * 4 + ks] = *(const short8*)
                        (Wp + (size_t)(384 + (jgp * 2 + j2) * 64 + kp * 16 + lr) * 128 + ks * 32 + lg * 8);
        float bvv[2][4];
        #pragma unroll
        for (int j2 = 0; j2 < 2; ++j2)
            #pragma unroll
            for (int kp = 0; kp < 4; ++kp)
                bvv[j2][kp] = bias[384 + (jgp * 2 + j2) * 64 + kp * 16 + lr];

        auto phase2 = [&](const unsigned short* __restrict__ xb, int t) {
            const int g0    = tok0 + t * 64;
            const int bb    = g0 >> 13;
            const int srow0 = bb * 16384 + 2 * (g0 & 8191);
            #pragma unroll
            for (int mf = 0; mf < 4; ++mf) {
                f32x4 a2[2][4];
                #pragma unroll
                for (int j2 = 0; j2 < 2; ++j2)
                    #pragma unroll
                    for (int kp = 0; kp < 4; ++kp)
                        a2[j2][kp] = (f32x4){0.f, 0.f, 0.f, 0.f};
                #pragma unroll
                for (int ks = 0; ks < 4; ++ks) {
                    short8 af = *(const short8*)&xb[(mf * 16 + lr) * XSTR + ks * 32 + lg * 8];
                    #pragma unroll
                    for (int j2 = 0; j2 < 2; ++j2)
                        #pragma unroll
                        for (int kp = 0; kp < 4; ++kp)
                            a2[j2][kp] = __builtin_amdgcn_mfma_f32_16x16x32_bf16(
                                af, breg[(j2 * 4 + kp) * 4 + ks], a2[j2][kp], 0, 0, 0);
                }
                // combine + wave-private swizzled obuf
                const int sw = (lg & 1) << 4;
                #pragma unroll
                for (int j2 = 0; j2 < 2; ++j2) {
                    #pragma unroll
                    for (int r = 0; r < 4; ++r) {
                        const int tokL = lg * 4 + r;
                        const int tok  = mf * 16 + tokL;
                        f32x4 cl = *(const f32x4*)&coeffw[jgp][tok][0];
                        f32x4 ch = *(const f32x4*)&coeffw[jgp][tok][4];
                        const float a0 = a2[j2][0][r] + bvv[j2][0];
                        const float a1 = a2[j2][1][r] + bvv[j2][1];
                        const float a2v = a2[j2][2][r] + bvv[j2][2];
                        const float a3 = a2[j2][3][r] + bvv[j2][3];
                        const float o0 = cl[0] * a0 + cl[1] * a1 + cl[2] * a2v + cl[3] * a3;
                        const float o1 = ch[0] * a0 + ch[1] * a1 + ch[2] * a2v + ch[3] * a3;
                        const int base = tokL * 64 + j2 * 16 + lr;
                        obufs[jgp][(base     ) ^ sw] = o0;   // ro=0
                        obufs[jgp][(base + 32) ^ sw] = o1;   // ro=1
                    }
                }
                // coalesced copy to global: full 128B lines
                #pragma unroll
                for (int i = 0; i < 4; ++i) {
                    const int w    = i * 256 + l * 4;
                    const int phys = w ^ (((w >> 8) & 1) << 4);
                    f32x4 vv = *(const f32x4*)&obufs[jgp][phys];
                    const int tokL = i * 4 + (l >> 4);
                    const int row  = srow0 + 32 * mf + 2 * tokL + ((l >> 3) & 1);
                    *(f32x4*)(out + (size_t)row * 128 + jgp * 32 + (l & 7) * 4) = vv;
                }
            }
        };

        // prologue: stage tile0 (my 8 rows) + tile1 (16 rows)
        {
            float4 xv[4];
            stage8_load(x, tok0, 32 + jgp * 8, l, xv);
            stage8_write(xlds[0], 32 + jgp * 8, l, xv);
        }
        __syncthreads();                       // B1: x0 ready
        {
            float4 xv[4];
            stage8_load(x, tok0 + 64, jgp * 16, l, xv);
            stage8_write(xlds[1], jgp * 16, l, xv);
            stage8_load(x, tok0 + 64, jgp * 16 + 8, l, xv);
            stage8_write(xlds[1], jgp * 16 + 8, l, xv);
        }
        __syncthreads();                       // B2

        for (int t = 0; t < T_TILES; ++t) {
            float4 xv[4];
            const bool do_stage = (t < T_TILES - 2);
            if (do_stage) stage8_load(x, tok0 + (t + 2) * 64, 32 + jgp * 8, l, xv);
            // finalize coeffs for tile t (wave-private copy)
            {
                const int pb = t & 1;
                float s[8];
                #pragma unroll
                for (int c = 0; c < 8; ++c) s[c] = 0.f;
                #pragma unroll
                for (int dcc = 0; dcc < 4; ++dcc) {
                    const float* pr = &partial[pb][dcc][l][0];
                    #pragma unroll
                    for (int c = 0; c < 8; ++c) s[c] += pr[c];
                }
                f32x4 c0 = {s[0] * 0.125f, s[1] * 0.125f, s[2] * 0.125f, s[3] * 0.125f};
                f32x4 c1 = {s[4] * 0.125f, s[5] * 0.125f, s[6] * 0.125f, s[7] * 0.125f};
                *(f32x4*)&coeffw[jgp][l][0] = c0;
                *(f32x4*)&coeffw[jgp][l][4] = c1;
            }
            phase2(xlds[t % 3], t);
            if (do_stage) stage8_write(xlds[(t + 2) % 3], 32 + jgp * 8, l, xv);
            __syncthreads();
        }
    }
}

extern "C" void kernel_launch(void* const* d_in, const int* in_sizes, int n_in,
                              void* d_out, int out_size, void* d_ws, size_t ws_size,
                              hipStream_t stream)
{
    (void)in_sizes; (void)n_in; (void)out_size; (void)ws_size;
    const float* x  = (const float*)d_in[0];
    const float* Wq = (const float*)d_in[1];
    const float* bq = (const float*)d_in[2];
    const float* Wk = (const float*)d_in[3];
    const float* bk = (const float*)d_in[4];
    const float* Wv = (const float*)d_in[5];
    const float* bv = (const float*)d_in[6];
    const float* Wo = (const float*)d_in[7];

    unsigned short* Wp   = (unsigned short*)d_ws;                    // 896*128 bf16
    float*          bias = (float*)((char*)d_ws + 896 * 128 * 2);    // 896 fp32

    prep_weights<<<896, 128, 0, stream>>>(Wq, bq, Wk, bk, Wv, bv, Wo, Wp, bias);
    fused_attn_kernel<<<256, 512, 0, stream>>>(x, Wp, bias, (float*)d_out);
}

// Round 5
// 56.346 us; speedup vs baseline: 4.3862x; 1.0901x over previous
//
#include <hip/hip_runtime.h>
#include <stdint.h>

// B=16, S=8192, DIM=128, H=4, KV=2, D=64; tokens = 131072; out [16,16384,128] fp32.
//
// Per token t: Y[896] = W' x_t + bias:
//   ch [0,256):   q, ch = h*64+d
//   ch [256,384): k, ch-256 = kv*64+d
//   ch [384,896): vproj, ch-384 = jg*64 + kp*16 + jm  (kp=kv*2+p)
//        j-remap for float2 stores: j = (jg>>1)*32 + jm*2 + (jg&1)
// coeff[t][ro*4+kp] = 0.125 * sum_d q[2ro+p,d]*k[kv,d]*qmean[d]
// out[row(2t+ro), j] = sum_kp coeff * vproj
//
// Structure: 256 blocks x 512 thr (8 waves), 1 block/CU. Waves 0-3 = qk
// (phase1, swapped-operand MFMA, B-in-regs), waves 4-7 = vproj (phase2,
// B-in-regs, direct wide stores). 8 tiles of 64 tokens per block, software
// pipeline, one NO-DRAIN barrier per iteration (lgkmcnt only — global
// stores stay in flight across barriers).

using short8 = __attribute__((ext_vector_type(8))) short;
using f32x4  = __attribute__((ext_vector_type(4))) float;

constexpr int XSTR = 136;     // bf16 elems per x-row in LDS (128+8)
constexpr int PSTR = 12;      // floats per partial row
constexpr int T_TILES = 8;

__device__ __forceinline__ unsigned short f2bf(float f) {
    unsigned int u = __float_as_uint(f);
    u += 0x7FFFu + ((u >> 16) & 1u);          // RNE
    return (unsigned short)(u >> 16);
}

// Barrier that waits only on LDS traffic; global stores remain in flight.
__device__ __forceinline__ void barrier_nodrain() {
    asm volatile("s_waitcnt lgkmcnt(0)\n\ts_barrier" ::: "memory");
}

// ---------------- prep: build W' (bf16 [896][128]) and bias (fp32 [896]) ----------------
__global__ void prep_weights(const float* __restrict__ Wq, const float* __restrict__ bq,
                             const float* __restrict__ Wk, const float* __restrict__ bk,
                             const float* __restrict__ Wv, const float* __restrict__ bv,
                             const float* __restrict__ Wo,
                             unsigned short* __restrict__ Wp, float* __restrict__ bias)
{
    const int ch = blockIdx.x;      // 0..895
    const int c  = threadIdx.x;     // 0..127
    float w, b;
    if (ch < 256) {                 // q
        const int hh = ch & 3, dd = ch >> 2;
        w = Wq[(hh * 64 + dd) * 128 + c];
        b = bq[hh * 64 + dd];
    } else if (ch < 384) {          // k
        const int i = ch - 256;
        const int kvh = i & 1, dd = i >> 1;
        w = Wk[(kvh * 64 + dd) * 128 + c];
        b = bk[kvh * 64 + dd];
    } else {                        // vproj, kp-interleaved, j-remapped
        const int i  = ch - 384;
        const int jg = i >> 6, kp = (i >> 4) & 3, jm = i & 15;
        const int j  = (jg >> 1) * 32 + jm * 2 + (jg & 1);   // float2-store remap
        const int kv = kp >> 1, p = kp & 1;
        float acc = 0.f, bacc = 0.f;
        #pragma unroll 8
        for (int d = 0; d < 64; ++d) {
            const int idx = kv * 64 + d;
            const int kvh = idx & 1, dd = idx >> 1;
            const float wo = Wo[j * 128 + p * 64 + d];
            acc  += wo * Wv[(kvh * 64 + dd) * 128 + c];
            bacc += wo * bv[kvh * 64 + dd];
        }
        w = acc; b = bacc;
    }
    Wp[ch * 128 + c] = f2bf(w);
    if (c == 0) bias[ch] = b;
}

// ---- x staging helpers: 8 rows per wave, issue-early / write-late (T14) ----
__device__ __forceinline__ void stage8_load(const float* __restrict__ x, int tb, int row0,
                                            int l, float4* xv)
{
    const int row = row0 + (l >> 3);
    const float* src = x + (size_t)(tb + row) * 128 + (l & 7) * 4;
    #pragma unroll
    for (int j = 0; j < 4; ++j) xv[j] = *(const float4*)(src + 32 * j);
}
__device__ __forceinline__ void stage8_write(unsigned short* __restrict__ xb, int row0,
                                             int l, const float4* xv)
{
    const int row = row0 + (l >> 3);
    #pragma unroll
    for (int j = 0; j < 4; ++j) {
        ushort4 s;
        s.x = f2bf(xv[j].x); s.y = f2bf(xv[j].y); s.z = f2bf(xv[j].z); s.w = f2bf(xv[j].w);
        *(ushort4*)&xb[row * XSTR + (l & 7) * 4 + 32 * j] = s;
    }
}

// ---------------- fused main kernel ----------------
__global__ __launch_bounds__(512, 2)
void fused_attn_kernel(const float* __restrict__ x,
                       const unsigned short* __restrict__ Wp,
                       const float* __restrict__ bias,
                       float* __restrict__ out)
{
    __shared__ __align__(16) unsigned short xlds[3][64 * XSTR];       // 52224 B
    __shared__ __align__(16) float partial[2][4][64][PSTR];           // 24576 B
    __shared__ __align__(16) float coeffw[4][64][8];                  //  8192 B

    const int tid = threadIdx.x;
    const int l   = tid & 63;
    const int wv  = tid >> 6;           // 0..7
    const int lr  = l & 15, lg = l >> 4;
    const int tok0 = blockIdx.x * (T_TILES * 64);

    if (wv < 4) {
        // ================= qk waves: phase1 producer =================
        const int dc = wv;
        int chb[6];
        #pragma unroll
        for (int n = 0; n < 4; ++n) chb[n] = n * 64 + dc * 16;
        chb[4] = 256 + dc * 16;
        chb[5] = 320 + dc * 16;

        short8 areg[24];
        #pragma unroll
        for (int n = 0; n < 6; ++n)
            #pragma unroll
            for (int ks = 0; ks < 4; ++ks)
                areg[n * 4 + ks] = *(const short8*)(Wp + (size_t)(chb[n] + lr) * 128 + ks * 32 + lg * 8);
        f32x4 biasv[6];
        #pragma unroll
        for (int n = 0; n < 6; ++n)
            biasv[n] = *(const f32x4*)(bias + chb[n] + lg * 4);

        auto phase1 = [&](const unsigned short* __restrict__ xb, int pb) {
            #pragma unroll
            for (int th = 0; th < 2; ++th) {
                f32x4 acc[2][6];
                #pragma unroll
                for (int ti = 0; ti < 2; ++ti)
                    #pragma unroll
                    for (int n = 0; n < 6; ++n)
                        acc[ti][n] = (f32x4){0.f, 0.f, 0.f, 0.f};
                #pragma unroll
                for (int ks = 0; ks < 4; ++ks) {
                    #pragma unroll
                    for (int ti = 0; ti < 2; ++ti) {
                        const int tf = th * 2 + ti;
                        short8 bfr = *(const short8*)&xb[(tf * 16 + lr) * XSTR + ks * 32 + lg * 8];
                        #pragma unroll
                        for (int n = 0; n < 6; ++n)
                            acc[ti][n] = __builtin_amdgcn_mfma_f32_16x16x32_bf16(
                                areg[n * 4 + ks], bfr, acc[ti][n], 0, 0, 0);
                    }
                }
                #pragma unroll
                for (int ti = 0; ti < 2; ++ti) {
                    const int tf = th * 2 + ti;
                    float pa[8];
                    #pragma unroll
                    for (int c = 0; c < 8; ++c) pa[c] = 0.f;
                    #pragma unroll
                    for (int r = 0; r < 4; ++r) {
                        const float q0 = acc[ti][0][r] + biasv[0][r];
                        const float q1 = acc[ti][1][r] + biasv[1][r];
                        const float q2 = acc[ti][2][r] + biasv[2][r];
                        const float q3 = acc[ti][3][r] + biasv[3][r];
                        const float k0v = acc[ti][4][r] + biasv[4][r];
                        const float k1v = acc[ti][5][r] + biasv[5][r];
                        const float qm  = 0.25f * (q0 + q1 + q2 + q3);
                        const float kt0 = k0v * qm, kt1 = k1v * qm;
                        pa[0] += q0 * kt0; pa[1] += q1 * kt0;
                        pa[2] += q0 * kt1; pa[3] += q1 * kt1;
                        pa[4] += q2 * kt0; pa[5] += q3 * kt0;
                        pa[6] += q2 * kt1; pa[7] += q3 * kt1;
                    }
                    #pragma unroll
                    for (int c = 0; c < 8; ++c) pa[c] += __shfl_xor(pa[c], 16);
                    #pragma unroll
                    for (int c = 0; c < 8; ++c) pa[c] += __shfl_xor(pa[c], 32);
                    if (lg == 0) {
                        f32x4 p0 = {pa[0], pa[1], pa[2], pa[3]};
                        f32x4 p1 = {pa[4], pa[5], pa[6], pa[7]};
                        float* dst = &partial[pb][dc][tf * 16 + lr][0];
                        *(f32x4*)(dst)     = p0;
                        *(f32x4*)(dst + 4) = p1;
                    }
                }
            }
        };

        // prologue
        {
            float4 xv[4];
            stage8_load(x, tok0, wv * 8, l, xv);
            stage8_write(xlds[0], wv * 8, l, xv);
        }
        barrier_nodrain();                     // B1: x0 ready
        phase1(xlds[0], 0);
        barrier_nodrain();                     // B2: partial[0] + x1 ready

        for (int t = 0; t < T_TILES; ++t) {
            float4 xv[4];
            const bool do_stage = (t < T_TILES - 2);
            if (do_stage) stage8_load(x, tok0 + (t + 2) * 64, wv * 8, l, xv);
            if (t < T_TILES - 1) phase1(xlds[(t + 1) % 3], (t + 1) & 1);
            if (do_stage) stage8_write(xlds[(t + 2) % 3], wv * 8, l, xv);
            barrier_nodrain();
        }
    } else {
        // ================= v waves: phase2 consumer =================
        const int jgp = wv - 4;

        short8 breg[32];                       // [(j2*4+kp)*4 + ks]
        #pragma unroll
        for (int j2 = 0; j2 < 2; ++j2)
            #pragma unroll
            for (int kp = 0; kp < 4; ++kp)
                #pragma unroll
                for (int ks = 0; ks < 4; ++ks)
                    breg[(j2 * 4 + kp) * 4 + ks] = *(const short8*)
                        (Wp + (size_t)(384 + (jgp * 2 + j2) * 64 + kp * 16 + lr) * 128 + ks * 32 + lg * 8);
        float bvv[2][4];
        #pragma unroll
        for (int j2 = 0; j2 < 2; ++j2)
            #pragma unroll
            for (int kp = 0; kp < 4; ++kp)
                bvv[j2][kp] = bias[384 + (jgp * 2 + j2) * 64 + kp * 16 + lr];

        auto phase2 = [&](const unsigned short* __restrict__ xb, int t) {
            const int g0    = tok0 + t * 64;
            const int bb    = g0 >> 13;
            const int srow0 = bb * 16384 + 2 * (g0 & 8191);
            #pragma unroll
            for (int mf = 0; mf < 4; ++mf) {
                f32x4 a2[2][4];
                #pragma unroll
                for (int j2 = 0; j2 < 2; ++j2)
                    #pragma unroll
                    for (int kp = 0; kp < 4; ++kp)
                        a2[j2][kp] = (f32x4){0.f, 0.f, 0.f, 0.f};
                #pragma unroll
                for (int ks = 0; ks < 4; ++ks) {
                    short8 af = *(const short8*)&xb[(mf * 16 + lr) * XSTR + ks * 32 + lg * 8];
                    #pragma unroll
                    for (int j2 = 0; j2 < 2; ++j2)
                        #pragma unroll
                        for (int kp = 0; kp < 4; ++kp)
                            a2[j2][kp] = __builtin_amdgcn_mfma_f32_16x16x32_bf16(
                                af, breg[(j2 * 4 + kp) * 4 + ks], a2[j2][kp], 0, 0, 0);
                }
                // combine + direct float2 stores (lane pair j = jgp*32 + lr*2 + j2)
                #pragma unroll
                for (int r = 0; r < 4; ++r) {
                    const int tokL = lg * 4 + r;
                    const int tok  = mf * 16 + tokL;
                    f32x4 cl = *(const f32x4*)&coeffw[jgp][tok][0];
                    f32x4 ch = *(const f32x4*)&coeffw[jgp][tok][4];
                    float2 s0, s1;
                    {
                        const float a0 = a2[0][0][r] + bvv[0][0];
                        const float a1 = a2[0][1][r] + bvv[0][1];
                        const float av = a2[0][2][r] + bvv[0][2];
                        const float a3 = a2[0][3][r] + bvv[0][3];
                        s0.x = cl[0] * a0 + cl[1] * a1 + cl[2] * av + cl[3] * a3;
                        s1.x = ch[0] * a0 + ch[1] * a1 + ch[2] * av + ch[3] * a3;
                    }
                    {
                        const float a0 = a2[1][0][r] + bvv[1][0];
                        const float a1 = a2[1][1][r] + bvv[1][1];
                        const float av = a2[1][2][r] + bvv[1][2];
                        const float a3 = a2[1][3][r] + bvv[1][3];
                        s0.y = cl[0] * a0 + cl[1] * a1 + cl[2] * av + cl[3] * a3;
                        s1.y = ch[0] * a0 + ch[1] * a1 + ch[2] * av + ch[3] * a3;
                    }
                    const int row = srow0 + 32 * mf + 2 * tokL;
                    float* dst = out + (size_t)row * 128 + jgp * 32 + lr * 2;
                    *(float2*)(dst)       = s0;   // ro=0
                    *(float2*)(dst + 128) = s1;   // ro=1
                }
            }
        };

        // prologue: stage tile0 (my 8 rows) + tile1 (16 rows)
        {
            float4 xv[4];
            stage8_load(x, tok0, 32 + jgp * 8, l, xv);
            stage8_write(xlds[0], 32 + jgp * 8, l, xv);
        }
        barrier_nodrain();                     // B1: x0 ready
        {
            float4 xv[4];
            stage8_load(x, tok0 + 64, jgp * 16, l, xv);
            stage8_write(xlds[1], jgp * 16, l, xv);
            stage8_load(x, tok0 + 64, jgp * 16 + 8, l, xv);
            stage8_write(xlds[1], jgp * 16 + 8, l, xv);
        }
        barrier_nodrain();                     // B2

        for (int t = 0; t < T_TILES; ++t) {
            float4 xv[4];
            const bool do_stage = (t < T_TILES - 2);
            if (do_stage) stage8_load(x, tok0 + (t + 2) * 64, 32 + jgp * 8, l, xv);
            // finalize coeffs for tile t (wave-private copy)
            {
                const int pb = t & 1;
                float s[8];
                #pragma unroll
                for (int c = 0; c < 8; ++c) s[c] = 0.f;
                #pragma unroll
                for (int dcc = 0; dcc < 4; ++dcc) {
                    const float* pr = &partial[pb][dcc][l][0];
                    #pragma unroll
                    for (int c = 0; c < 8; ++c) s[c] += pr[c];
                }
                f32x4 c0 = {s[0] * 0.125f, s[1] * 0.125f, s[2] * 0.125f, s[3] * 0.125f};
                f32x4 c1 = {s[4] * 0.125f, s[5] * 0.125f, s[6] * 0.125f, s[7] * 0.125f};
                *(f32x4*)&coeffw[jgp][l][0] = c0;
                *(f32x4*)&coeffw[jgp][l][4] = c1;
            }
            phase2(xlds[t % 3], t);
            if (do_stage) stage8_write(xlds[(t + 2) % 3], 32 + jgp * 8, l, xv);
            barrier_nodrain();
        }
    }
}

extern "C" void kernel_launch(void* const* d_in, const int* in_sizes, int n_in,
                              void* d_out, int out_size, void* d_ws, size_t ws_size,
                              hipStream_t stream)
{
    (void)in_sizes; (void)n_in; (void)out_size; (void)ws_size;
    const float* x  = (const float*)d_in[0];
    const float* Wq = (const float*)d_in[1];
    const float* bq = (const float*)d_in[2];
    const float* Wk = (const float*)d_in[3];
    const float* bk = (const float*)d_in[4];
    const float* Wv = (const float*)d_in[5];
    const float* bv = (const float*)d_in[6];
    const float* Wo = (const float*)d_in[7];

    unsigned short* Wp   = (unsigned short*)d_ws;                    // 896*128 bf16
    float*          bias = (float*)((char*)d_ws + 896 * 128 * 2);    // 896 fp32

    prep_weights<<<896, 128, 0, stream>>>(Wq, bq, Wk, bk, Wv, bv, Wo, Wp, bias);
    fused_attn_kernel<<<256, 512, 0, stream>>>(x, Wp, bias, (float*)d_out);
}